// Round 10
// baseline (3522.072 us; speedup 1.0000x reference)
//
#include <hip/hip_runtime.h>
#include <hip/hip_fp16.h>

// ---------------------------------------------------------------------------
// LSTM position predictor, persistent cooperative kernel. Round 13.
//   r12 never ran: volatile generic-pointer LDS access trips a gfx950
//   codegen bug (V_CMP_NE_U32 on $src_shared_base). LESSON: use
//   __hip_atomic_load/store with WORKGROUP scope for LDS flags (lowers to
//   plain ds ops), never volatile on dynamic-LDS pointers.
//   ROUND 13 = r12's design, compilable:
//   COMMS-WAVE SPECIALIZATION (NTHR 512 -> 576, wave 8 = comms):
//   - Wave 8 alone sweeps the 256 IF arrival slots (r10's exact proven
//     sc0 sc1 dwordx4 + ballot), publishing per-K-group levels to LDS as
//     each 64-producer group completes (early start preserved).
//   - Compute waves spin on LDS flags (workgroup-scope atomic ds_read +
//     s_sleep): IF pollers drop 2048 -> 256 waves (~8x less fabric poll
//     traffic), detection adds ~100ns LDS hop.
//   - All barriers stay block-wide (comms wave participates; its poll sits
//     between the same barrier pair as the compute waves' wait+gemm).
//   Hypothesis under test (unmeasured since r7): the 2048-wave sc0sc1 poll
//   storm (~1.5 TB/s of pure poll reads on 16 lines) inflates every IF
//   round-trip 3-4x. Cross-block signaling stays sc0sc1-both-sides (the
//   only proven primitive; r5/r8/r11 all hung on L2-local flag variants).
//   Kept from r10 (passed, 3491us): tiled write-once h16 ring
//   [gen][grp=bid][batch][8], no steady-state inv, one-time entry
//   buffer_inv, plain-load prefetch w/ compiler fine-grained vmcnt (no full
//   drain), pre-wait hoisting, fused fc GEMM, folded rank-4 input, fp16
//   weights in LDS, LDS-only intra-step barriers, sc0sc1 arrive stores.
// ---------------------------------------------------------------------------

#define HID   2048
#define NBAT  64
#define TENC  128
#define TDEC  64
#define NBLK  256
#define NTHR  576   // 8 gemm waves + 1 comms wave
#define WROW  2056  // f16 per LDS weight row (+8 pad, 16B aligned)
#define FROW  2056  // f16 per fcT row

typedef _Float16 f16;
typedef _Float16 f16x8 __attribute__((ext_vector_type(8)));
typedef _Float16 f16x4 __attribute__((ext_vector_type(4)));
typedef float    f32x4v __attribute__((ext_vector_type(4)));

// LDS layout (bytes):
//   0      : wlds  32 x 2056 f16      = 131584
//   131584 : gbuf  [64][36] f32       =   9216
//   140800 : xv    [64][4]  f32       =   1024
//   141824 : wsm   [32][4]  f32       =    512
//   142336 : bsm   [32]     f32       =    128
//   142464 : fcp   [64][4]  f32       =   1024
//   143488 : fcT   [4][2056] f16      =  16448
//   159936 : lds_lvl int[4]           =     16
#define SMEM_BYTES 159952

#define DOT4(a,b) ((a).x*(b).x + (a).y*(b).y + (a).z*(b).z + (a).w*(b).w)

struct Params {
  const float* x; const int* lengths;
  const float* enc_Wih; const float* enc_Whh; const float* enc_bih; const float* enc_bhh;
  const float* emb_W; const float* emb_b;
  const float* dec_Wih; const float* dec_Whh; const float* dec_bih; const float* dec_bhh;
  const float* fc_W; const float* fc_b;
  float* dst;        // 278784 floats: preds[64][64][4], out[64][4], h[64][2048], c[64][2048]
  f16* h16;          // ws: ring of 193 gen buffers (or 2 in fallback), tiled [gen][grp][batch][8]
  unsigned* bar;     // ws: per-block arrival level slots [0..255]
  int ring;          // 1 = write-once ring (cached reads); 0 = 2-buf bypass loads
};

__device__ __forceinline__ void astore_u64(f16* p, unsigned long long v) {
  __hip_atomic_store((unsigned long long*)p, v, __ATOMIC_RELAXED, __HIP_MEMORY_SCOPE_AGENT);
}
__device__ __forceinline__ f16x8 bload_f16x8(const f16* p) {   // IF-bypass load, left in flight
  f16x8 r;
  asm volatile("global_load_dwordx4 %0, %1, off sc0 sc1" : "=v"(r) : "v"(p));
  return r;
}
__device__ __forceinline__ uint4 aload_u32x4(const unsigned* p) {  // IF-coherent sweep
  uint4 r;
  asm volatile("global_load_dwordx4 %0, %1, off sc0 sc1\n\ts_waitcnt vmcnt(0)"
               : "=v"(r) : "v"(p) : "memory");
  return r;
}
// LDS flag ops: workgroup-scope atomics -> plain ds_read/ds_write (no
// volatile generic-pointer codegen bug).
__device__ __forceinline__ int lds_ld(const int* p) {
  return __hip_atomic_load(p, __ATOMIC_RELAXED, __HIP_MEMORY_SCOPE_WORKGROUP);
}
__device__ __forceinline__ void lds_st(int* p, int v) {
  __hip_atomic_store(p, v, __ATOMIC_RELAXED, __HIP_MEMORY_SCOPE_WORKGROUP);
}
// Block-local barrier that drains ONLY LDS (keeps vmem prefetch in flight).
__device__ __forceinline__ void ldsbar() {
  asm volatile("s_waitcnt lgkmcnt(0)" ::: "memory");
  __builtin_amdgcn_s_barrier();
}
// Full drain + scheduling fence (rule #18) - asm-load path and epilogue only.
__device__ __forceinline__ void waitpa() {
  asm volatile("s_waitcnt vmcnt(0)" ::: "memory");
  __builtin_amdgcn_sched_barrier(0);
}

// --- sync -----------------------------------------------------------------
// Arrival: publish this block's level to its IF slot (t==0, AFTER
// __syncthreads drained every wave's h16 stores). sc0 sc1 both sides: the
// ONLY proven cross-block signaling primitive on this chip.
__device__ __forceinline__ void arrive(unsigned* bar, int bid, unsigned level) {
  asm volatile("global_store_dword %0, %1, off sc0 sc1\n\ts_waitcnt vmcnt(0)"
               :: "v"(bar + bid), "v"(level) : "memory");
}
// Comms wave: sweep all 256 slots at IF; publish LDS level for group g the
// moment its 64 producers (slots g*64..g*64+63 = lanes g*16..g*16+15) done.
__device__ __forceinline__ void comms_poll(const unsigned* bar, unsigned level,
                                           int l, int* lds_lvl) {
  const unsigned* slots = bar + l * 4;
  unsigned pub = 0;
  for (;;) {
    uint4 v = aload_u32x4(slots);
    int ok = (v.x >= level) & (v.y >= level) & (v.z >= level) & (v.w >= level);
    unsigned long long bal = __ballot(ok);
    #pragma unroll
    for (int g = 0; g < 4; ++g) {
      if (!(pub & (1u << g)) && ((bal >> (g * 16)) & 0xFFFFull) == 0xFFFFull) {
        if (l == 0) lds_st(&lds_lvl[g], (int)level);
        pub |= (1u << g);
      }
    }
    if (pub == 0xFu) break;
    __builtin_amdgcn_s_sleep(2);
  }
  asm volatile("s_waitcnt lgkmcnt(0)" ::: "memory");   // ds_write landed
}
// Compute wave: spin on this kq group's LDS level (no fabric traffic).
__device__ __forceinline__ void spin_lds(const int* f, int level) {
  while (lds_ld(f) < level) __builtin_amdgcn_s_sleep(1);
}

// Convert this block's 32 gate rows of W (fp32 [8192][2048]) into LDS fp16.
__device__ __forceinline__ void fill_weights(const float* __restrict__ W, int bid,
                                             f16* wlds, int w, int l) {
  #pragma unroll
  for (int rr = 0; rr < 4; ++rr) {
    int r  = w * 4 + rr;
    int gr = ((r >> 3) << 11) + bid * 8 + (r & 7);
    const float4* src = (const float4*)(W + (size_t)gr * HID);
    f16* dst = wlds + (size_t)r * WROW;
    #pragma unroll
    for (int it = 0; it < 8; ++it) {
      float4 v = src[it * 64 + l];
      f16x4 h4; h4[0] = (f16)v.x; h4[1] = (f16)v.y; h4[2] = (f16)v.z; h4[3] = (f16)v.w;
      *(f16x4*)(dst + (it * 64 + l) * 4) = h4;
    }
  }
}

// Issue ALL h16 A-fragment loads for this wave (tiled layout).
// Ring mode: plain cached loads; compiler inserts fine-grained per-use vmcnt.
__device__ __forceinline__ void gemm_prefetch(const f16* __restrict__ hp, int ring,
                                              int w, int l15, int quad,
                                              f16x8* pa0, f16x8* pa1) {
  const int mh = w & 1, kq = w >> 1;
  const f16* A0 = hp + ((size_t)(kq * 64 + quad)) * 512 + (size_t)(mh * 32 + l15) * 8;
  if (ring) {
    #pragma unroll
    for (int ch = 0; ch < 16; ++ch) {
      pa0[ch] = *(const f16x8*)(A0 + ch * 2048);
      pa1[ch] = *(const f16x8*)(A0 + ch * 2048 + 128);
    }
  } else {              // fallback: IF-bypass asm loads (caller must waitpa())
    #pragma unroll
    for (int ch = 0; ch < 16; ++ch) {
      pa0[ch] = bload_f16x8(A0 + ch * 2048);
      pa1[ch] = bload_f16x8(A0 + ch * 2048 + 128);
    }
  }
}

// fc partial: out[b][d] += sum_k h[b][k] * fcW[d][k] over this wave's fragment.
__device__ __forceinline__ void fc_compute(const f16* fcT, float* fcp,
                                           int w, int l15, int quad,
                                           const f16x8* pa0, const f16x8* pa1) {
  const int mh = w & 1, kq = w >> 1;
  f32x4v f0 = {0.f, 0.f, 0.f, 0.f}, f1 = f0;
  const f16* BF = fcT + (size_t)l15 * FROW + kq * 512 + quad * 8;
  #pragma unroll
  for (int ch = 0; ch < 16; ++ch) {
    f16x8 vbF = {};
    if (l15 < 4) vbF = *(const f16x8*)(BF + ch * 32);
    f0 = __builtin_amdgcn_mfma_f32_16x16x32_f16(pa0[ch], vbF, f0, 0, 0, 0);
    f1 = __builtin_amdgcn_mfma_f32_16x16x32_f16(pa1[ch], vbF, f1, 0, 0, 0);
  }
  if (l15 < 4) {
    const int brow = mh * 32 + quad * 4;
    #pragma unroll
    for (int r = 0; r < 4; ++r) {
      unsafeAtomicAdd(&fcp[(brow + r) * 4 + l15],      f0[r]);
      unsafeAtomicAdd(&fcp[(brow + 16 + r) * 4 + l15], f1[r]);
    }
  }
}

// gates += h @ Whh.T for this block's 32 gate rows; optional fused fc partial.
template<bool FC>
__device__ __forceinline__ void gemm_compute(const f16* wlds, const f16* fcT,
                                             float* gbuf, float* fcp,
                                             int w, int l15, int quad,
                                             const f16x8* pa0, const f16x8* pa1) {
  const int mh = w & 1, kq = w >> 1;
  f32x4v a00 = {0.f, 0.f, 0.f, 0.f}, a01 = a00, a10 = a00, a11 = a00;
  const f16* B0 = wlds + (size_t)l15 * WROW + kq * 512 + quad * 8;
  const f16* B1 = B0 + (size_t)16 * WROW;
  #pragma unroll
  for (int ch = 0; ch < 16; ++ch) {
    f16x8 vb0 = *(const f16x8*)(B0 + ch * 32);
    f16x8 vb1 = *(const f16x8*)(B1 + ch * 32);
    a00 = __builtin_amdgcn_mfma_f32_16x16x32_f16(pa0[ch], vb0, a00, 0, 0, 0);
    a01 = __builtin_amdgcn_mfma_f32_16x16x32_f16(pa0[ch], vb1, a01, 0, 0, 0);
    a10 = __builtin_amdgcn_mfma_f32_16x16x32_f16(pa1[ch], vb0, a10, 0, 0, 0);
    a11 = __builtin_amdgcn_mfma_f32_16x16x32_f16(pa1[ch], vb1, a11, 0, 0, 0);
  }
  const int brow = mh * 32 + quad * 4;
  #pragma unroll
  for (int r = 0; r < 4; ++r) {
    unsafeAtomicAdd(&gbuf[(brow + r)      * 36 +      l15], a00[r]);
    unsafeAtomicAdd(&gbuf[(brow + r)      * 36 + 16 + l15], a01[r]);
    unsafeAtomicAdd(&gbuf[(brow + 16 + r) * 36 +      l15], a10[r]);
    unsafeAtomicAdd(&gbuf[(brow + 16 + r) * 36 + 16 + l15], a11[r]);
  }
  if (FC) fc_compute(fcT, fcp, w, l15, quad, pa0, pa1);
}

extern "C" __global__ void __launch_bounds__(NTHR, 1)
lstm_persistent(Params P) {
  extern __shared__ char smem[];
  f16*   wlds = (f16*)smem;
  float* gbuf = (float*)(smem + 131584);
  float* xv   = (float*)(smem + 140800);
  float* wsm  = (float*)(smem + 141824);
  float* bsm  = (float*)(smem + 142336);
  float* fcp  = (float*)(smem + 142464);
  f16*   fcT  = (f16*)(smem + 143488);
  int*   lds_lvl = (int*)(smem + 159936);

  const int t    = threadIdx.x;
  const int bid  = blockIdx.x;
  const int w    = t >> 6;
  const bool cw  = (w == 8);          // comms wave
  const int l    = t & 63;
  const int l15  = l & 15;
  const int quad = l >> 4;
  const int kq   = (w >> 1) & 3;
  const int bb   = t >> 3;
  const int jj   = t & 7;
  const int jglob = bid * 8 + jj;
  const int ring = P.ring;
  const size_t GEN = (size_t)NBAT * HID;   // f16 per generation buffer

  // ---------------- one-time cache scrub + LDS flag init -------------------
  if (t == 0) {
    lds_st(&lds_lvl[0], 0); lds_st(&lds_lvl[1], 0);
    lds_st(&lds_lvl[2], 0); lds_st(&lds_lvl[3], 0);
    // scrub: safe (r6-proven), no dirty lines exist at entry
    asm volatile("s_waitcnt vmcnt(0)\n\tbuffer_inv sc0 sc1\n\ts_waitcnt vmcnt(0)" ::: "memory");
  }
  __syncthreads();

  // ---------------- setup (block-local) ----------------
  if (t < 32) {
    int r = t, gr = ((r >> 3) << 11) + bid * 8 + (r & 7);
    ((float4*)wsm)[r] = ((const float4*)P.enc_Wih)[gr];
    bsm[r] = P.enc_bih[gr] + P.enc_bhh[gr];
  }
  if (!cw) fill_weights(P.enc_Whh, bid, wlds, w, l);

  const int len_b = cw ? 1 : P.lengths[bb];
  const float4 fcb = ((const float4*)P.fc_b)[0];
  float hreg = 0.f, creg = 0.f;

  // ---------------- encoder: 128 masked steps ----------------
  for (int ts = 0; ts < TENC; ++ts) {
    const size_t roff = (size_t)(ring ? ts : (ts & 1)) * GEN;
    const size_t woff = (size_t)(ring ? (ts + 1) : ((ts + 1) & 1)) * GEN;
    // --- pre-wait work (h-independent): x load, gbuf=bias, xv stage ---
    float4 xvv;
    if (t < NBAT) xvv = ((const float4*)P.x)[t * TENC + ts];
    for (int e = t; e < 2048; e += NTHR) {
      int b = e >> 5, n = e & 31;
      gbuf[b * 36 + n] = bsm[n];
    }
    if (t < NBAT) ((float4*)xv)[t] = xvv;
    ldsbar();                                   // gbuf + xv ready
    // --- wait for this wave's K-group of h_ts, prefetch, GEMM ---
    if (ts > 0) {
      if (cw) {
        comms_poll(P.bar, (unsigned)ts, l, lds_lvl);
      } else {
        spin_lds(lds_lvl + kq, ts);
        f16x8 pa0[16], pa1[16];
        gemm_prefetch(P.h16 + roff, ring, w, l15, quad, pa0, pa1);
        if (!ring) waitpa();    // asm loads need the explicit drain (rule #18)
        gemm_compute<false>(wlds, fcT, gbuf, fcp, w, l15, quad, pa0, pa1);
      }
    }
    ldsbar();
    if (!cw) {
      const float4 xb  = ((const float4*)xv)[bb];
      const float4 wi4 = ((const float4*)wsm)[jj];
      const float4 wf4 = ((const float4*)wsm)[8 + jj];
      const float4 wg4 = ((const float4*)wsm)[16 + jj];
      const float4 wo4 = ((const float4*)wsm)[24 + jj];
      float gi = gbuf[bb * 36 + jj]      + DOT4(xb, wi4);
      float gf = gbuf[bb * 36 + 8 + jj]  + DOT4(xb, wf4);
      float gg = gbuf[bb * 36 + 16 + jj] + DOT4(xb, wg4);
      float go = gbuf[bb * 36 + 24 + jj] + DOT4(xb, wo4);
      float ii = 1.f / (1.f + expf(-gi));
      float ff = 1.f / (1.f + expf(-gf));
      float g  = tanhf(gg);
      float oo = 1.f / (1.f + expf(-go));
      float cn = ff * creg + ii * g;
      float hn = oo * tanhf(cn);
      if (ts < len_b) { creg = cn; hreg = hn; }   // packed-sequence freeze
      unsigned hv = (unsigned)__builtin_bit_cast(unsigned short, (f16)hreg);
      unsigned v1 = __shfl_down(hv, 1), v2 = __shfl_down(hv, 2), v3 = __shfl_down(hv, 3);
      if ((t & 3) == 0) {   // tiled write: [grp=bid][batch=bb][8] -> full lines
        unsigned long long pk = (unsigned long long)hv | ((unsigned long long)v1 << 16)
                              | ((unsigned long long)v2 << 32) | ((unsigned long long)v3 << 48);
        astore_u64(P.h16 + woff + (size_t)bid * 512 + (size_t)bb * 8 + (jj & 4), pk);
      }
    }
    __syncthreads();                              // drains h16 stores (all waves)
    if (t == 0) arrive(P.bar, bid, (unsigned)(ts + 1));
  }

  // ------- transition (block-local; overlaps other XCDs' tails) -------
  if (!cw) {
    fill_weights(P.dec_Whh, bid, wlds, w, l);
    #pragma unroll
    for (int rr = 0; rr < 4; ++rr) {       // M1 = dec_Wih@emb_W straight into LDS
      int r = w * 4 + rr, gr = ((r >> 3) << 11) + bid * 8 + (r & 7);
      const float* wr = P.dec_Wih + (size_t)gr * HID;
      float a0 = 0.f, a1 = 0.f, a2 = 0.f, a3 = 0.f, ab = 0.f;
      for (int k = l; k < HID; k += 64) {
        float wv = wr[k];
        float4 e = ((const float4*)P.emb_W)[k];
        a0 += wv * e.x; a1 += wv * e.y; a2 += wv * e.z; a3 += wv * e.w;
        ab += wv * P.emb_b[k];
      }
      #pragma unroll
      for (int off = 32; off > 0; off >>= 1) {
        a0 += __shfl_xor(a0, off); a1 += __shfl_xor(a1, off);
        a2 += __shfl_xor(a2, off); a3 += __shfl_xor(a3, off);
        ab += __shfl_xor(ab, off);
      }
      if (l == 0) {
        wsm[r * 4 + 0] = a0; wsm[r * 4 + 1] = a1; wsm[r * 4 + 2] = a2; wsm[r * 4 + 3] = a3;
        bsm[r] = ab + P.dec_bih[gr] + P.dec_bhh[gr];
      }
    }
  }
  for (int i = t; i < 2048; i += NTHR) {   // fcT[d][k] = (f16)fc_W[d][k]
    int d = i >> 9, k4 = i & 511;
    float4 v = ((const float4*)P.fc_W)[i];
    f16x4 h4; h4[0] = (f16)v.x; h4[1] = (f16)v.y; h4[2] = (f16)v.z; h4[3] = (f16)v.w;
    *(f16x4*)(fcT + (size_t)d * FROW + k4 * 4) = h4;
  }
  ldsbar();   // block-local: wlds/wsm/bsm/fcT visible

  // ---------------- decoder: 64 autoregressive steps ----------------
  for (int s = 0; s < TDEC; ++s) {
    const int rgen = TENC + s, wgen = rgen + 1;
    const size_t roff = (size_t)(ring ? rgen : (rgen & 1)) * GEN;
    const size_t woff = (size_t)(ring ? wgen : (wgen & 1)) * GEN;
    // --- pre-wait work: fcp zero + gbuf=bias ---
    if (t < 256) fcp[t] = 0.f;
    for (int e = t; e < 2048; e += NTHR) {
      int b = e >> 5, n = e & 31;
      gbuf[b * 36 + n] = bsm[n];
    }
    ldsbar();
    // --- wait for h_rgen, then prefetch + GEMM (+fused fc) ---
    if (cw) {
      comms_poll(P.bar, (unsigned)rgen, l, lds_lvl);
    } else {
      spin_lds(lds_lvl + kq, rgen);
      f16x8 pa0[16], pa1[16];
      gemm_prefetch(P.h16 + roff, ring, w, l15, quad, pa0, pa1);
      if (!ring) waitpa();
      gemm_compute<true>(wlds, fcT, gbuf, fcp, w, l15, quad, pa0, pa1);
    }
    ldsbar();
    if (t < NBAT) {          // xv = input for this step = fc(h_prev) (or x0 at s==0)
      float4 o;
      if (s == 0) {
        o = ((const float4*)P.x)[t * TENC + (P.lengths[t] - 1)];
      } else {
        float4 p = ((const float4*)fcp)[t];
        o.x = fcb.x + p.x; o.y = fcb.y + p.y; o.z = fcb.z + p.z; o.w = fcb.w + p.w;
      }
      ((float4*)xv)[t] = o;
      if (s >= 1 && bid == s)                   // rotating prediction writer
        ((float4*)P.dst)[t * TDEC + (s - 1)] = o;
    }
    ldsbar();
    if (!cw) {
      const float4 xb  = ((const float4*)xv)[bb];
      const float4 wi4 = ((const float4*)wsm)[jj];
      const float4 wf4 = ((const float4*)wsm)[8 + jj];
      const float4 wg4 = ((const float4*)wsm)[16 + jj];
      const float4 wo4 = ((const float4*)wsm)[24 + jj];
      float gi = gbuf[bb * 36 + jj]      + DOT4(xb, wi4);
      float gf = gbuf[bb * 36 + 8 + jj]  + DOT4(xb, wf4);
      float gg = gbuf[bb * 36 + 16 + jj] + DOT4(xb, wg4);
      float go = gbuf[bb * 36 + 24 + jj] + DOT4(xb, wo4);
      float ii = 1.f / (1.f + expf(-gi));
      float ff = 1.f / (1.f + expf(-gf));
      float g  = tanhf(gg);
      float oo = 1.f / (1.f + expf(-go));
      creg = ff * creg + ii * g;
      hreg = oo * tanhf(creg);
      unsigned hv = (unsigned)__builtin_bit_cast(unsigned short, (f16)hreg);
      unsigned v1 = __shfl_down(hv, 1), v2 = __shfl_down(hv, 2), v3 = __shfl_down(hv, 3);
      if ((t & 3) == 0) {
        unsigned long long pk = (unsigned long long)hv | ((unsigned long long)v1 << 16)
                              | ((unsigned long long)v2 << 32) | ((unsigned long long)v3 << 48);
        astore_u64(P.h16 + woff + (size_t)bid * 512 + (size_t)bb * 8 + (jj & 4), pk);
      }
    }
    __syncthreads();
    if (t == 0) arrive(P.bar, bid, (unsigned)wgen);
  }

  // ---------------- epilogue: out(63) = fc(H_63) by block 0 ----------------
  if (bid == 0) {
    if (cw) comms_poll(P.bar, (unsigned)(TENC + TDEC), l, lds_lvl);
    else    spin_lds(lds_lvl + kq, TENC + TDEC);
    if (t < 256) fcp[t] = 0.f;
    f16x8 pa0[16], pa1[16];
    if (!cw)
      gemm_prefetch(P.h16 + (size_t)(ring ? (TENC + TDEC) : ((TENC + TDEC) & 1)) * GEN,
                    ring, w, l15, quad, pa0, pa1);
    ldsbar();
    waitpa();
    if (!cw) fc_compute(fcT, fcp, w, l15, quad, pa0, pa1);
    ldsbar();
    if (t < NBAT) {
      float4 p = ((const float4*)fcp)[t];
      float4 o;
      o.x = fcb.x + p.x; o.y = fcb.y + p.y; o.z = fcb.z + p.z; o.w = fcb.w + p.w;
      ((float4*)P.dst)[t * TDEC + 63] = o;       // predictions[b][63]
      ((float4*)(P.dst + 16384))[t]   = o;       // out
    }
  }
  if (!cw) {
    P.dst[16640  + (size_t)bb * HID + jglob] = hreg;   // h
    P.dst[147712 + (size_t)bb * HID + jglob] = creg;   // c
  }
}

extern "C" void kernel_launch(void* const* d_in, const int* in_sizes, int n_in,
                              void* d_out, int out_size, void* d_ws, size_t ws_size,
                              hipStream_t stream) {
  (void)in_sizes; (void)n_in; (void)out_size;
  Params P;
  P.x        = (const float*)d_in[0];
  P.lengths  = (const int*)  d_in[1];
  // d_in[2] = target_len (constant 64)
  P.enc_Wih  = (const float*)d_in[3];
  P.enc_Whh  = (const float*)d_in[4];
  P.enc_bih  = (const float*)d_in[5];
  P.enc_bhh  = (const float*)d_in[6];
  P.emb_W    = (const float*)d_in[7];
  P.emb_b    = (const float*)d_in[8];
  P.dec_Wih  = (const float*)d_in[9];
  P.dec_Whh  = (const float*)d_in[10];
  P.dec_bih  = (const float*)d_in[11];
  P.dec_bhh  = (const float*)d_in[12];
  P.fc_W     = (const float*)d_in[13];
  P.fc_b     = (const float*)d_in[14];
  P.dst      = (float*)d_out;

  char* ws = (char*)d_ws;
  const size_t slot = (size_t)NBAT * HID * sizeof(_Float16);   // 262144 B per generation
  const size_t ring_bytes = (size_t)(TENC + TDEC + 1) * slot;  // 193 slots = 50,593,792 B
  int ring = (ws_size >= ring_bytes + 16384) ? 1 : 0;
  P.h16  = (f16*)ws;
  P.bar  = (unsigned*)(ws + (ring ? ring_bytes : 2 * slot));
  P.ring = ring;

  hipMemsetAsync(P.bar, 0, 12288, stream);           // ws is poisoned 0xAA

  hipFuncSetAttribute((const void*)lstm_persistent,
                      hipFuncAttributeMaxDynamicSharedMemorySize, SMEM_BYTES);
  void* args[] = { &P };
  hipLaunchCooperativeKernel((const void*)lstm_persistent, dim3(NBLK), dim3(NTHR),
                             args, SMEM_BYTES, stream);
}

// Round 11
// 3489.650 us; speedup vs baseline: 1.0093x; 1.0093x over previous
//
#include <hip/hip_runtime.h>
#include <hip/hip_fp16.h>

// ---------------------------------------------------------------------------
// LSTM position predictor, persistent cooperative kernel. Round 14.
//   MEASUREMENT ROUND. r13 exonerated poll contention (2048->256 pollers,
//   flat). Five mechanism rounds flat/small while the bottom-up model says
//   ~6-8us/step vs 18 measured. Before optimizing further, measure the one
//   quantity every theory hinges on: the cost of ONE sync round-trip on the
//   critical chain, under real load.
//   WITHIN-ROUND A/B: a dispatch counter lives in ws OUTSIDE the memset'd
//   bar region. All blocks read it at entry (race-free: the only writer is
//   block 0 AFTER the level-192 grid sync of the PREVIOUS dispatch);
//   variant = ctr & 1 alternates per dispatch:
//     A (even): byte-identical r10 path (verified baseline, 3491us).
//     B (odd):  r10 + ONE extra arrive (store+ack RT) per producer step
//               + ONE extra slot-gather (read RT) per consumer wait.
//               Idempotent re-stores/re-reads -> correct by construction.
//   Readout: rocprof per-dispatch dur. Top-5 = B mode; headline = blend.
//   Delta(B-A)/192 = RT_store + RT_gather. Decision tree documented in the
//   round notes: nominal (~1.6us) -> attack load/LDS/jitter next; inflated
//   (~4-6us) -> attack RT COUNT next (merge arrival into data, etc).
//   Kernel base = r10 EXACTLY (tiled write-once h16 ring, no steady-state
//   inv, one-time entry buffer_inv, per-wave K-slice dataflow sync sc0sc1
//   both sides, plain-load prefetch w/ compiler fine-grained vmcnt, pre-wait
//   hoisting, fused fc GEMM, folded rank-4 input, fp16 weights in LDS,
//   LDS-only intra-step barriers). 512 threads (r13's 576 was neutral).
// ---------------------------------------------------------------------------

#define HID   2048
#define NBAT  64
#define TENC  128
#define TDEC  64
#define NBLK  256
#define NTHR  512
#define WROW  2056   // f16 per LDS weight row (+8 pad, 16B aligned)
#define FROW  2056   // f16 per fcT row

typedef _Float16 f16;
typedef _Float16 f16x8 __attribute__((ext_vector_type(8)));
typedef _Float16 f16x4 __attribute__((ext_vector_type(4)));
typedef float    f32x4v __attribute__((ext_vector_type(4)));

// LDS layout (bytes):
//   0      : wlds  32 x 2056 f16      = 131584
//   131584 : gbuf  [64][36] f32       =   9216
//   140800 : xv    [64][4]  f32       =   1024
//   141824 : wsm   [32][4]  f32       =    512
//   142336 : bsm   [32]     f32       =    128
//   142464 : fcp   [64][4]  f32       =   1024
//   143488 : fcT   [4][2056] f16      =  16448
//   159936 : vbflag int               =      4
#define SMEM_BYTES 159952

#define DOT4(a,b) ((a).x*(b).x + (a).y*(b).y + (a).z*(b).z + (a).w*(b).w)

struct Params {
  const float* x; const int* lengths;
  const float* enc_Wih; const float* enc_Whh; const float* enc_bih; const float* enc_bhh;
  const float* emb_W; const float* emb_b;
  const float* dec_Wih; const float* dec_Whh; const float* dec_bih; const float* dec_bhh;
  const float* fc_W; const float* fc_b;
  float* dst;        // 278784 floats: preds[64][64][4], out[64][4], h[64][2048], c[64][2048]
  f16* h16;          // ws: ring of 193 gen buffers (or 2 in fallback), tiled [gen][grp][batch][8]
  unsigned* bar;     // ws: per-block level slots [0..255]; ctr at [3072] (NOT memset)
  int ring;          // 1 = write-once ring (cached reads); 0 = 2-buf bypass loads
};

__device__ __forceinline__ void astore_u64(f16* p, unsigned long long v) {
  __hip_atomic_store((unsigned long long*)p, v, __ATOMIC_RELAXED, __HIP_MEMORY_SCOPE_AGENT);
}
__device__ __forceinline__ f16x8 bload_f16x8(const f16* p) {   // IF-bypass load, left in flight
  f16x8 r;
  asm volatile("global_load_dwordx4 %0, %1, off sc0 sc1" : "=v"(r) : "v"(p));
  return r;
}
__device__ __forceinline__ unsigned load_sc01(const unsigned* p) {
  unsigned r;
  asm volatile("global_load_dword %0, %1, off sc0 sc1\n\ts_waitcnt vmcnt(0)"
               : "=v"(r) : "v"(p) : "memory");
  return r;
}
__device__ __forceinline__ void store_sc01(unsigned* p, unsigned v) {
  asm volatile("global_store_dword %0, %1, off sc0 sc1\n\ts_waitcnt vmcnt(0)"
               :: "v"(p), "v"(v) : "memory");
}
// Block-local barrier that drains ONLY LDS (keeps vmem prefetch in flight).
__device__ __forceinline__ void ldsbar() {
  asm volatile("s_waitcnt lgkmcnt(0)" ::: "memory");
  __builtin_amdgcn_s_barrier();
}
// Full drain + scheduling fence (rule #18) - asm-load path and epilogue only.
__device__ __forceinline__ void waitpa() {
  asm volatile("s_waitcnt vmcnt(0)" ::: "memory");
  __builtin_amdgcn_sched_barrier(0);
}

// --- dataflow sync (r7/r10-proven; poll and store at the SAME coherence
// point: sc0 sc1 both sides — the only proven cross-block primitive) -------
// Wave-slice wait: lane l polls producer block (kq*64 + l)'s level slot.
// VB: probe variant — one extra mandatory gather RT after detection.
__device__ __forceinline__ void wait_slice(const unsigned* bar, int kq, int l,
                                           unsigned level, int VB) {
  const unsigned* slot = bar + (kq << 6) + l;
  for (;;) {
    unsigned v;
    asm volatile("global_load_dword %0, %1, off sc0 sc1\n\ts_waitcnt vmcnt(0)"
                 : "=v"(v) : "v"(slot) : "memory");
    if (v >= level) break;
    __builtin_amdgcn_s_sleep(1);
  }
  if (VB) {   // B: one extra full gather round-trip (idempotent re-read)
    unsigned v;
    asm volatile("global_load_dword %0, %1, off sc0 sc1\n\ts_waitcnt vmcnt(0)"
                 : "=v"(v) : "v"(slot) : "memory");
    asm volatile("" :: "v"(v));   // keep live (rule #17)
  }
}
// Arrival: publish this block's level (t==0, AFTER __syncthreads drained all
// waves' h16 stores). VB: one extra store+ack round-trip (same value).
__device__ __forceinline__ void arrive(unsigned* bar, int bid, unsigned level, int VB) {
  asm volatile("s_waitcnt vmcnt(0)" ::: "memory");
  asm volatile("global_store_dword %0, %1, off sc0 sc1\n\ts_waitcnt vmcnt(0)"
               :: "v"(bar + bid), "v"(level) : "memory");
  if (VB)
    asm volatile("global_store_dword %0, %1, off sc0 sc1\n\ts_waitcnt vmcnt(0)"
                 :: "v"(bar + bid), "v"(level) : "memory");
}

// Convert this block's 32 gate rows of W (fp32 [8192][2048]) into LDS fp16.
__device__ __forceinline__ void fill_weights(const float* __restrict__ W, int bid,
                                             f16* wlds, int w, int l) {
  #pragma unroll
  for (int rr = 0; rr < 4; ++rr) {
    int r  = w * 4 + rr;
    int gr = ((r >> 3) << 11) + bid * 8 + (r & 7);
    const float4* src = (const float4*)(W + (size_t)gr * HID);
    f16* dst = wlds + (size_t)r * WROW;
    #pragma unroll
    for (int it = 0; it < 8; ++it) {
      float4 v = src[it * 64 + l];
      f16x4 h4; h4[0] = (f16)v.x; h4[1] = (f16)v.y; h4[2] = (f16)v.z; h4[3] = (f16)v.w;
      *(f16x4*)(dst + (it * 64 + l) * 4) = h4;
    }
  }
}

// Issue ALL h16 A-fragment loads for this wave (tiled layout).
// Ring mode: plain cached loads; compiler inserts fine-grained per-use vmcnt.
__device__ __forceinline__ void gemm_prefetch(const f16* __restrict__ hp, int ring,
                                              int w, int l15, int quad,
                                              f16x8* pa0, f16x8* pa1) {
  const int mh = w & 1, kq = w >> 1;
  const f16* A0 = hp + ((size_t)(kq * 64 + quad)) * 512 + (size_t)(mh * 32 + l15) * 8;
  if (ring) {
    #pragma unroll
    for (int ch = 0; ch < 16; ++ch) {
      pa0[ch] = *(const f16x8*)(A0 + ch * 2048);
      pa1[ch] = *(const f16x8*)(A0 + ch * 2048 + 128);
    }
  } else {              // fallback: IF-bypass asm loads (caller must waitpa())
    #pragma unroll
    for (int ch = 0; ch < 16; ++ch) {
      pa0[ch] = bload_f16x8(A0 + ch * 2048);
      pa1[ch] = bload_f16x8(A0 + ch * 2048 + 128);
    }
  }
}

// fc partial: out[b][d] += sum_k h[b][k] * fcW[d][k] over this wave's fragment.
__device__ __forceinline__ void fc_compute(const f16* fcT, float* fcp,
                                           int w, int l15, int quad,
                                           const f16x8* pa0, const f16x8* pa1) {
  const int mh = w & 1, kq = w >> 1;
  f32x4v f0 = {0.f, 0.f, 0.f, 0.f}, f1 = f0;
  const f16* BF = fcT + (size_t)l15 * FROW + kq * 512 + quad * 8;
  #pragma unroll
  for (int ch = 0; ch < 16; ++ch) {
    f16x8 vbF = {};
    if (l15 < 4) vbF = *(const f16x8*)(BF + ch * 32);
    f0 = __builtin_amdgcn_mfma_f32_16x16x32_f16(pa0[ch], vbF, f0, 0, 0, 0);
    f1 = __builtin_amdgcn_mfma_f32_16x16x32_f16(pa1[ch], vbF, f1, 0, 0, 0);
  }
  if (l15 < 4) {
    const int brow = mh * 32 + quad * 4;
    #pragma unroll
    for (int r = 0; r < 4; ++r) {
      unsafeAtomicAdd(&fcp[(brow + r) * 4 + l15],      f0[r]);
      unsafeAtomicAdd(&fcp[(brow + 16 + r) * 4 + l15], f1[r]);
    }
  }
}

// gates += h @ Whh.T for this block's 32 gate rows; optional fused fc partial.
template<bool FC>
__device__ __forceinline__ void gemm_compute(const f16* wlds, const f16* fcT,
                                             float* gbuf, float* fcp,
                                             int w, int l15, int quad,
                                             const f16x8* pa0, const f16x8* pa1) {
  const int mh = w & 1, kq = w >> 1;
  f32x4v a00 = {0.f, 0.f, 0.f, 0.f}, a01 = a00, a10 = a00, a11 = a00;
  const f16* B0 = wlds + (size_t)l15 * WROW + kq * 512 + quad * 8;
  const f16* B1 = B0 + (size_t)16 * WROW;
  #pragma unroll
  for (int ch = 0; ch < 16; ++ch) {
    f16x8 vb0 = *(const f16x8*)(B0 + ch * 32);
    f16x8 vb1 = *(const f16x8*)(B1 + ch * 32);
    a00 = __builtin_amdgcn_mfma_f32_16x16x32_f16(pa0[ch], vb0, a00, 0, 0, 0);
    a01 = __builtin_amdgcn_mfma_f32_16x16x32_f16(pa0[ch], vb1, a01, 0, 0, 0);
    a10 = __builtin_amdgcn_mfma_f32_16x16x32_f16(pa1[ch], vb0, a10, 0, 0, 0);
    a11 = __builtin_amdgcn_mfma_f32_16x16x32_f16(pa1[ch], vb1, a11, 0, 0, 0);
  }
  const int brow = mh * 32 + quad * 4;
  #pragma unroll
  for (int r = 0; r < 4; ++r) {
    unsafeAtomicAdd(&gbuf[(brow + r)      * 36 +      l15], a00[r]);
    unsafeAtomicAdd(&gbuf[(brow + r)      * 36 + 16 + l15], a01[r]);
    unsafeAtomicAdd(&gbuf[(brow + 16 + r) * 36 +      l15], a10[r]);
    unsafeAtomicAdd(&gbuf[(brow + 16 + r) * 36 + 16 + l15], a11[r]);
  }
  if (FC) fc_compute(fcT, fcp, w, l15, quad, pa0, pa1);
}

extern "C" __global__ void __launch_bounds__(NTHR, 2)
lstm_persistent(Params P) {
  extern __shared__ char smem[];
  f16*   wlds = (f16*)smem;
  float* gbuf = (float*)(smem + 131584);
  float* xv   = (float*)(smem + 140800);
  float* wsm  = (float*)(smem + 141824);
  float* bsm  = (float*)(smem + 142336);
  float* fcp  = (float*)(smem + 142464);
  f16*   fcT  = (f16*)(smem + 143488);
  int*   vbp  = (int*)(smem + 159936);

  const int t    = threadIdx.x;
  const int bid  = blockIdx.x;
  const int w    = t >> 6;
  const int l    = t & 63;
  const int l15  = l & 15;
  const int quad = l >> 4;
  const int kq   = w >> 1;
  const int bb   = t >> 3;
  const int jj   = t & 7;
  const int jglob = bid * 8 + jj;
  const int ring = P.ring;
  const size_t GEN = (size_t)NBAT * HID;   // f16 per generation buffer
  unsigned* ctr  = P.bar + 3072;           // outside the 12288B memset

  // ---------------- variant read + one-time cache scrub --------------------
  // ctr race-free: only writer is block 0 of the PREVIOUS dispatch, after
  // its level-192 grid sync (all blocks of this dispatch start fresh).
  if (t == 0) {
    unsigned v = load_sc01(ctr);
    *vbp = (int)(v & 1u);
    // scrub: safe (r6-proven), no dirty lines exist at entry
    asm volatile("s_waitcnt vmcnt(0)\n\tbuffer_inv sc0 sc1\n\ts_waitcnt vmcnt(0)" ::: "memory");
  }
  __syncthreads();
  const int VB = *vbp;    // 0 = baseline r10 path, 1 = +1 RT store +1 RT read

  // ---------------- setup (block-local) ----------------
  if (t < 32) {
    int r = t, gr = ((r >> 3) << 11) + bid * 8 + (r & 7);
    ((float4*)wsm)[r] = ((const float4*)P.enc_Wih)[gr];
    bsm[r] = P.enc_bih[gr] + P.enc_bhh[gr];
  }
  fill_weights(P.enc_Whh, bid, wlds, w, l);

  const int len_b = P.lengths[bb];
  const float4 fcb = ((const float4*)P.fc_b)[0];
  float hreg = 0.f, creg = 0.f;

  // ---------------- encoder: 128 masked steps ----------------
  for (int ts = 0; ts < TENC; ++ts) {
    const size_t roff = (size_t)(ring ? ts : (ts & 1)) * GEN;
    const size_t woff = (size_t)(ring ? (ts + 1) : ((ts + 1) & 1)) * GEN;
    // --- pre-wait work (h-independent): x load, gbuf=bias, xv stage ---
    float4 xvv;
    if (t < NBAT) xvv = ((const float4*)P.x)[t * TENC + ts];
    for (int e = t; e < 2048; e += NTHR) {
      int b = e >> 5, n = e & 31;
      gbuf[b * 36 + n] = bsm[n];
    }
    if (t < NBAT) ((float4*)xv)[t] = xvv;
    ldsbar();                                   // gbuf + xv ready
    // --- wait for this wave's K-slice of h_ts, prefetch, GEMM ---
    if (ts > 0) {
      wait_slice(P.bar, kq, l, (unsigned)ts, VB);
      f16x8 pa0[16], pa1[16];
      gemm_prefetch(P.h16 + roff, ring, w, l15, quad, pa0, pa1);
      if (!ring) waitpa();    // asm loads need the explicit drain (rule #18)
      gemm_compute<false>(wlds, fcT, gbuf, fcp, w, l15, quad, pa0, pa1);
    }
    ldsbar();
    {
      const float4 xb  = ((const float4*)xv)[bb];
      const float4 wi4 = ((const float4*)wsm)[jj];
      const float4 wf4 = ((const float4*)wsm)[8 + jj];
      const float4 wg4 = ((const float4*)wsm)[16 + jj];
      const float4 wo4 = ((const float4*)wsm)[24 + jj];
      float gi = gbuf[bb * 36 + jj]      + DOT4(xb, wi4);
      float gf = gbuf[bb * 36 + 8 + jj]  + DOT4(xb, wf4);
      float gg = gbuf[bb * 36 + 16 + jj] + DOT4(xb, wg4);
      float go = gbuf[bb * 36 + 24 + jj] + DOT4(xb, wo4);
      float ii = 1.f / (1.f + expf(-gi));
      float ff = 1.f / (1.f + expf(-gf));
      float g  = tanhf(gg);
      float oo = 1.f / (1.f + expf(-go));
      float cn = ff * creg + ii * g;
      float hn = oo * tanhf(cn);
      if (ts < len_b) { creg = cn; hreg = hn; }   // packed-sequence freeze
      unsigned hv = (unsigned)__builtin_bit_cast(unsigned short, (f16)hreg);
      unsigned v1 = __shfl_down(hv, 1), v2 = __shfl_down(hv, 2), v3 = __shfl_down(hv, 3);
      if ((t & 3) == 0) {   // tiled write: [grp=bid][batch=bb][8] -> full lines
        unsigned long long pk = (unsigned long long)hv | ((unsigned long long)v1 << 16)
                              | ((unsigned long long)v2 << 32) | ((unsigned long long)v3 << 48);
        astore_u64(P.h16 + woff + (size_t)bid * 512 + (size_t)bb * 8 + (jj & 4), pk);
      }
    }
    __syncthreads();                              // drains h16 stores (all waves)
    if (t == 0) arrive(P.bar, bid, (unsigned)(ts + 1), VB);
  }

  // ------- transition (block-local; overlaps other XCDs' tails) -------
  fill_weights(P.dec_Whh, bid, wlds, w, l);
  #pragma unroll
  for (int rr = 0; rr < 4; ++rr) {       // M1 = dec_Wih@emb_W straight into LDS
    int r = w * 4 + rr, gr = ((r >> 3) << 11) + bid * 8 + (r & 7);
    const float* wr = P.dec_Wih + (size_t)gr * HID;
    float a0 = 0.f, a1 = 0.f, a2 = 0.f, a3 = 0.f, ab = 0.f;
    for (int k = l; k < HID; k += 64) {
      float wv = wr[k];
      float4 e = ((const float4*)P.emb_W)[k];
      a0 += wv * e.x; a1 += wv * e.y; a2 += wv * e.z; a3 += wv * e.w;
      ab += wv * P.emb_b[k];
    }
    #pragma unroll
    for (int off = 32; off > 0; off >>= 1) {
      a0 += __shfl_xor(a0, off); a1 += __shfl_xor(a1, off);
      a2 += __shfl_xor(a2, off); a3 += __shfl_xor(a3, off);
      ab += __shfl_xor(ab, off);
    }
    if (l == 0) {
      wsm[r * 4 + 0] = a0; wsm[r * 4 + 1] = a1; wsm[r * 4 + 2] = a2; wsm[r * 4 + 3] = a3;
      bsm[r] = ab + P.dec_bih[gr] + P.dec_bhh[gr];
    }
  }
  for (int i = t; i < 2048; i += NTHR) {   // fcT[d][k] = (f16)fc_W[d][k]
    int d = i >> 9, k4 = i & 511;
    float4 v = ((const float4*)P.fc_W)[i];
    f16x4 h4; h4[0] = (f16)v.x; h4[1] = (f16)v.y; h4[2] = (f16)v.z; h4[3] = (f16)v.w;
    *(f16x4*)(fcT + (size_t)d * FROW + k4 * 4) = h4;
  }
  ldsbar();   // block-local: wlds/wsm/bsm/fcT visible

  // ---------------- decoder: 64 autoregressive steps ----------------
  for (int s = 0; s < TDEC; ++s) {
    const int rgen = TENC + s, wgen = rgen + 1;
    const size_t roff = (size_t)(ring ? rgen : (rgen & 1)) * GEN;
    const size_t woff = (size_t)(ring ? wgen : (wgen & 1)) * GEN;
    // --- pre-wait work: fcp zero + gbuf=bias ---
    if (t < 256) fcp[t] = 0.f;
    for (int e = t; e < 2048; e += NTHR) {
      int b = e >> 5, n = e & 31;
      gbuf[b * 36 + n] = bsm[n];
    }
    ldsbar();
    // --- wait for h_rgen, then prefetch + GEMM (+fused fc) ---
    wait_slice(P.bar, kq, l, (unsigned)rgen, VB);
    f16x8 pa0[16], pa1[16];
    gemm_prefetch(P.h16 + roff, ring, w, l15, quad, pa0, pa1);
    if (!ring) waitpa();
    gemm_compute<true>(wlds, fcT, gbuf, fcp, w, l15, quad, pa0, pa1);
    ldsbar();
    if (t < NBAT) {          // xv = input for this step = fc(h_prev) (or x0 at s==0)
      float4 o;
      if (s == 0) {
        o = ((const float4*)P.x)[t * TENC + (P.lengths[t] - 1)];
      } else {
        float4 p = ((const float4*)fcp)[t];
        o.x = fcb.x + p.x; o.y = fcb.y + p.y; o.z = fcb.z + p.z; o.w = fcb.w + p.w;
      }
      ((float4*)xv)[t] = o;
      if (s >= 1 && bid == s)                   // rotating prediction writer
        ((float4*)P.dst)[t * TDEC + (s - 1)] = o;
    }
    ldsbar();
    {
      const float4 xb  = ((const float4*)xv)[bb];
      const float4 wi4 = ((const float4*)wsm)[jj];
      const float4 wf4 = ((const float4*)wsm)[8 + jj];
      const float4 wg4 = ((const float4*)wsm)[16 + jj];
      const float4 wo4 = ((const float4*)wsm)[24 + jj];
      float gi = gbuf[bb * 36 + jj]      + DOT4(xb, wi4);
      float gf = gbuf[bb * 36 + 8 + jj]  + DOT4(xb, wf4);
      float gg = gbuf[bb * 36 + 16 + jj] + DOT4(xb, wg4);
      float go = gbuf[bb * 36 + 24 + jj] + DOT4(xb, wo4);
      float ii = 1.f / (1.f + expf(-gi));
      float ff = 1.f / (1.f + expf(-gf));
      float g  = tanhf(gg);
      float oo = 1.f / (1.f + expf(-go));
      creg = ff * creg + ii * g;
      hreg = oo * tanhf(creg);
      unsigned hv = (unsigned)__builtin_bit_cast(unsigned short, (f16)hreg);
      unsigned v1 = __shfl_down(hv, 1), v2 = __shfl_down(hv, 2), v3 = __shfl_down(hv, 3);
      if ((t & 3) == 0) {
        unsigned long long pk = (unsigned long long)hv | ((unsigned long long)v1 << 16)
                              | ((unsigned long long)v2 << 32) | ((unsigned long long)v3 << 48);
        astore_u64(P.h16 + woff + (size_t)bid * 512 + (size_t)bb * 8 + (jj & 4), pk);
      }
    }
    __syncthreads();
    if (t == 0) arrive(P.bar, bid, (unsigned)wgen, VB);
  }

  // ---------------- epilogue: out(63) = fc(H_63) by block 0 ----------------
  if (bid == 0) {
    wait_slice(P.bar, kq, l, (unsigned)(TENC + TDEC), 0);
    if (t < 256) fcp[t] = 0.f;
    f16x8 pa0[16], pa1[16];
    gemm_prefetch(P.h16 + (size_t)(ring ? (TENC + TDEC) : ((TENC + TDEC) & 1)) * GEN,
                  ring, w, l15, quad, pa0, pa1);
    ldsbar();
    waitpa();
    fc_compute(fcT, fcp, w, l15, quad, pa0, pa1);
    ldsbar();
    if (t < NBAT) {
      float4 p = ((const float4*)fcp)[t];
      float4 o;
      o.x = fcb.x + p.x; o.y = fcb.y + p.y; o.z = fcb.z + p.z; o.w = fcb.w + p.w;
      ((float4*)P.dst)[t * TDEC + 63] = o;       // predictions[b][63]
      ((float4*)(P.dst + 16384))[t]   = o;       // out
    }
    // advance the dispatch counter for the NEXT dispatch (all blocks of this
    // dispatch read ctr long ago — they've passed 192 grid levels since).
    if (t == 0) {
      unsigned v = load_sc01(ctr);
      store_sc01(ctr, v + 1u);
    }
  }
  P.dst[16640  + (size_t)bb * HID + jglob] = hreg;   // h
  P.dst[147712 + (size_t)bb * HID + jglob] = creg;   // c
}

extern "C" void kernel_launch(void* const* d_in, const int* in_sizes, int n_in,
                              void* d_out, int out_size, void* d_ws, size_t ws_size,
                              hipStream_t stream) {
  (void)in_sizes; (void)n_in; (void)out_size;
  Params P;
  P.x        = (const float*)d_in[0];
  P.lengths  = (const int*)  d_in[1];
  // d_in[2] = target_len (constant 64)
  P.enc_Wih  = (const float*)d_in[3];
  P.enc_Whh  = (const float*)d_in[4];
  P.enc_bih  = (const float*)d_in[5];
  P.enc_bhh  = (const float*)d_in[6];
  P.emb_W    = (const float*)d_in[7];
  P.emb_b    = (const float*)d_in[8];
  P.dec_Wih  = (const float*)d_in[9];
  P.dec_Whh  = (const float*)d_in[10];
  P.dec_bih  = (const float*)d_in[11];
  P.dec_bhh  = (const float*)d_in[12];
  P.fc_W     = (const float*)d_in[13];
  P.fc_b     = (const float*)d_in[14];
  P.dst      = (float*)d_out;

  char* ws = (char*)d_ws;
  const size_t slot = (size_t)NBAT * HID * sizeof(_Float16);   // 262144 B per generation
  const size_t ring_bytes = (size_t)(TENC + TDEC + 1) * slot;  // 193 slots = 50,593,792 B
  int ring = (ws_size >= ring_bytes + 16384) ? 1 : 0;
  P.h16  = (f16*)ws;
  P.bar  = (unsigned*)(ws + (ring ? ring_bytes : 2 * slot));
  P.ring = ring;

  // memset ONLY the 12288B sync region; the dispatch counter at bar[3072]
  // (byte 12288, inside the 16KB reservation) persists across dispatches.
  hipMemsetAsync(P.bar, 0, 12288, stream);           // ws is poisoned 0xAA

  hipFuncSetAttribute((const void*)lstm_persistent,
                      hipFuncAttributeMaxDynamicSharedMemorySize, SMEM_BYTES);
  void* args[] = { &P };
  hipLaunchCooperativeKernel((const void*)lstm_persistent, dim3(NBLK), dim3(NTHR),
                             args, SMEM_BYTES, stream);
}